// Round 1
// baseline (441.041 us; speedup 1.0000x reference)
//
#include <hip/hip_runtime.h>
#include <cstdint>
#include <cstddef>

typedef __bf16 bf16;
typedef bf16 bf16x4 __attribute__((ext_vector_type(4)));
typedef bf16 bf16x8 __attribute__((ext_vector_type(8)));
typedef float f32x4 __attribute__((ext_vector_type(4)));

#define SEQ 4096
#define DIMD 1024

// async global->LDS, 16 bytes per lane. LDS dest must be wave-uniform base + lane*16.
__device__ __forceinline__ void async16(void* lds, const void* g) {
    __builtin_amdgcn_global_load_lds(
        (__attribute__((address_space(1))) void*)g,
        (__attribute__((address_space(3))) void*)lds,
        16, 0, 0);
}

// Core 128x128 GEMM tile, BK=32, 256 threads (4 waves, 2x2 wave grid, 4x4 MFMA tiles/wave).
// C[m,n] = sum_k A[m,k] * B[n,k]   (B given row-major over n, i.e. "B^T input")
__device__ __forceinline__ void gemm_core(
    const bf16* __restrict__ Ag, long lda, int rowA0,
    const bf16* __restrict__ Bg, long ldb, int rowB0,
    int kIters, f32x4 acc[4][4])
{
    __shared__ bf16 lA[128 * 32];
    __shared__ bf16 lB[128 * 32];
    const int tid  = threadIdx.x;
    const int lane = tid & 63;
    const int wid  = tid >> 6;
    const int wm   = (wid >> 1) * 64;
    const int wn   = (wid & 1) * 64;
    const int lr   = lane & 15;
    const int kq   = (lane >> 4) * 8;

    for (int kk = 0; kk < kIters; ++kk) {
        const long k0 = (long)kk * 32;
        // stage A tile (128x32) and B tile (128x32): 512 chunks of 16B each, 2+2 per thread
#pragma unroll
        for (int i = 0; i < 2; ++i) {
            const int c   = tid + i * 256;
            const int row = c >> 2;
            const int ko  = (c & 3) * 8;
            async16(&lA[c * 8], Ag + (long)(rowA0 + row) * lda + k0 + ko);
            async16(&lB[c * 8], Bg + (long)(rowB0 + row) * ldb + k0 + ko);
        }
        __syncthreads();

        bf16x8 af[4], bfr[4];
#pragma unroll
        for (int mi = 0; mi < 4; ++mi)
            af[mi] = *(const bf16x8*)&lA[(wm + mi * 16 + lr) * 32 + kq];
#pragma unroll
        for (int ni = 0; ni < 4; ++ni)
            bfr[ni] = *(const bf16x8*)&lB[(wn + ni * 16 + lr) * 32 + kq];
#pragma unroll
        for (int mi = 0; mi < 4; ++mi)
#pragma unroll
            for (int ni = 0; ni < 4; ++ni)
                acc[mi][ni] = __builtin_amdgcn_mfma_f32_16x16x32_bf16(
                    af[mi], bfr[ni], acc[mi][ni], 0, 0, 0);
        __syncthreads();
    }
}

// fp32 -> bf16 elementwise, 4 per thread
__global__ __launch_bounds__(256) void cvt_kernel(const float* __restrict__ in,
                                                  bf16* __restrict__ out, int n4)
{
    int i = blockIdx.x * 256 + threadIdx.x;
    if (i >= n4) return;
    const float4 v = ((const float4*)in)[i];
    bf16x4 o = { (bf16)v.x, (bf16)v.y, (bf16)v.z, (bf16)v.w };
    ((bf16x4*)out)[i] = o;
}

// QKV projection: C[m, n] = sum_k x[m,k] W[n,k] + b[n], m in [0,8192), n in [0,3072)
// routes n<1024 -> Q[m][n], n<2048 -> K[m][n-1024], else V transposed Vt[b][d][s]
__global__ __launch_bounds__(256) void qkv_gemm(
    const bf16* __restrict__ xb, const bf16* __restrict__ wb,
    const float* __restrict__ bias,
    bf16* __restrict__ Qb, bf16* __restrict__ Kb, bf16* __restrict__ Vt)
{
    const int bm = blockIdx.y * 128, bn = blockIdx.x * 128;
    f32x4 acc[4][4] = {};
    gemm_core(xb, DIMD, bm, wb, DIMD, bn, DIMD / 32, acc);

    const int tid = threadIdx.x, lane = tid & 63, wid = tid >> 6;
    const int wm = (wid >> 1) * 64, wn = (wid & 1) * 64;
    const int lr = lane & 15, q4 = (lane >> 4) * 4;
#pragma unroll
    for (int ni = 0; ni < 4; ++ni) {
        const int n = bn + wn + ni * 16 + lr;
        const float bv = bias[n];
#pragma unroll
        for (int mi = 0; mi < 4; ++mi) {
#pragma unroll
            for (int r = 0; r < 4; ++r) {
                const int m = bm + wm + mi * 16 + q4 + r;
                const bf16 o = (bf16)(acc[mi][ni][r] + bv);
                if (n < 1024) {
                    Qb[(long)m * DIMD + n] = o;
                } else if (n < 2048) {
                    Kb[(long)m * DIMD + (n - 1024)] = o;
                } else {
                    const int b = m >> 12, s = m & 4095;
                    Vt[((long)b * DIMD + (n - 2048)) * SEQ + s] = o;
                }
            }
        }
    }
}

// scores for one batch: P[q][key] = (key<=q) ? exp( (Q.K^T)[q][key] / 32 ) : 0, bf16
__global__ __launch_bounds__(256) void score_kernel(
    const bf16* __restrict__ Q, const bf16* __restrict__ K, bf16* __restrict__ P)
{
    const int bq = blockIdx.y * 128, bk = blockIdx.x * 128;
    if (bk > bq) return;  // fully masked tile: never written, never read downstream
    f32x4 acc[4][4] = {};
    gemm_core(Q, DIMD, bq, K, DIMD, bk, DIMD / 32, acc);

    const int tid = threadIdx.x, lane = tid & 63, wid = tid >> 6;
    const int wm = (wid >> 1) * 64, wn = (wid & 1) * 64;
    const int lr = lane & 15, q4 = (lane >> 4) * 4;
#pragma unroll
    for (int mi = 0; mi < 4; ++mi) {
#pragma unroll
        for (int r = 0; r < 4; ++r) {
            const int q = bq + wm + mi * 16 + q4 + r;
#pragma unroll
            for (int ni = 0; ni < 4; ++ni) {
                const int key = bk + wn + ni * 16 + lr;
                const float s = acc[mi][ni][r] * 0.03125f;  // 1/sqrt(1024)
                // scores ~N(0,1): no max-subtraction needed, exp() cannot overflow
                const float p = (key <= q) ? __expf(s) : 0.0f;
                P[(long)q * SEQ + key] = (bf16)p;
            }
        }
    }
}

// inv[q] = 1 / sum_j P[q][j];  one wave per row
__global__ __launch_bounds__(256) void rowsum_kernel(const bf16* __restrict__ P,
                                                     float* __restrict__ inv)
{
    const int wid = threadIdx.x >> 6, lane = threadIdx.x & 63;
    const int q = blockIdx.x * 4 + wid;
    float s = 0.f;
    // chunks starting <= q stay inside written tiles; masked slots inside them are 0
    for (int j0 = lane * 8; j0 <= q; j0 += 512) {
        const bf16x8 v = *(const bf16x8*)&P[(long)q * SEQ + j0];
#pragma unroll
        for (int e = 0; e < 8; ++e) s += (float)v[e];
    }
#pragma unroll
    for (int off = 32; off; off >>= 1) s += __shfl_down(s, off);
    if (lane == 0) inv[q] = 1.0f / s;
}

// Y[q][d] = inv[q] * sum_j P[q][j] * Vt[d][j]; K extent = (q_tile+1)*128
__global__ __launch_bounds__(256) void pv_kernel(
    const bf16* __restrict__ P, const bf16* __restrict__ Vt,
    const float* __restrict__ inv, float* __restrict__ Y)
{
    const int bq = blockIdx.y * 128, bd = blockIdx.x * 128;
    f32x4 acc[4][4] = {};
    gemm_core(P, SEQ, bq, Vt, SEQ, bd, (blockIdx.y + 1) * 4, acc);

    const int tid = threadIdx.x, lane = tid & 63, wid = tid >> 6;
    const int wm = (wid >> 1) * 64, wn = (wid & 1) * 64;
    const int lr = lane & 15, q4 = (lane >> 4) * 4;
#pragma unroll
    for (int mi = 0; mi < 4; ++mi) {
#pragma unroll
        for (int r = 0; r < 4; ++r) {
            const int q = bq + wm + mi * 16 + q4 + r;
            const float iv = inv[q];
#pragma unroll
            for (int ni = 0; ni < 4; ++ni) {
                const int d = bd + wn + ni * 16 + lr;
                Y[(long)q * DIMD + d] = acc[mi][ni][r] * iv;
            }
        }
    }
}

extern "C" void kernel_launch(void* const* d_in, const int* in_sizes, int n_in,
                              void* d_out, int out_size, void* d_ws, size_t ws_size,
                              hipStream_t stream)
{
    const float* x    = (const float*)d_in[0];   // [2,4096,1024]
    const float* W    = (const float*)d_in[1];   // [3072,1024]
    const float* bqkv = (const float*)d_in[2];   // [3072]
    float* out = (float*)d_out;                  // [2,4096,1024] fp32
    char* ws = (char*)d_ws;

    // workspace layout (~80 MB). xb/wb are transient and overlap the P region:
    // P is only written after qkv_gemm has consumed xb/wb (stream-ordered).
    bf16* P   = (bf16*)(ws);                         // 4096*4096*2   = 32 MB (per-batch reuse)
    bf16* xb  = (bf16*)(ws);                         // 8192*1024*2   = 16 MB (transient)
    bf16* wb  = (bf16*)(ws + 16777216);              // 3072*1024*2   =  6 MB (transient)
    bf16* Qb  = (bf16*)(ws + 33554432);              // 16 MB
    bf16* Kb  = (bf16*)(ws + 50331648);              // 16 MB
    bf16* Vt  = (bf16*)(ws + 67108864);              // 16 MB, [b][d][s]
    float* inv = (float*)(ws + 83886080);            // 16 KB

    cvt_kernel<<<8192, 256, 0, stream>>>(x, xb, 8192 * 1024 / 4);
    cvt_kernel<<<3072, 256, 0, stream>>>(W, wb, 3072 * 1024 / 4);
    qkv_gemm<<<dim3(24, 64), 256, 0, stream>>>(xb, wb, bqkv, Qb, Kb, Vt);

    for (int b = 0; b < 2; ++b) {
        const bf16* Qp = Qb + (long)b * SEQ * DIMD;
        const bf16* Kp = Kb + (long)b * SEQ * DIMD;
        const bf16* Vp = Vt + (long)b * DIMD * SEQ;
        score_kernel<<<dim3(32, 32), 256, 0, stream>>>(Qp, Kp, P);
        rowsum_kernel<<<1024, 256, 0, stream>>>(P, inv);
        pv_kernel<<<dim3(8, 32), 256, 0, stream>>>(P, Vp, inv, out + (long)b * SEQ * DIMD);
    }
}

// Round 2
// 349.495 us; speedup vs baseline: 1.2619x; 1.2619x over previous
//
#include <hip/hip_runtime.h>
#include <cstdint>
#include <cstddef>

typedef __bf16 bf16;
typedef bf16 bf16x4 __attribute__((ext_vector_type(4)));
typedef bf16 bf16x8 __attribute__((ext_vector_type(8)));
typedef float f32x4 __attribute__((ext_vector_type(4)));

#define SEQ 4096
#define DIMD 1024

// async global->LDS, 16 bytes per lane. LDS dest must be wave-uniform base + lane*16.
__device__ __forceinline__ void async16(void* lds, const void* g) {
    __builtin_amdgcn_global_load_lds(
        (__attribute__((address_space(1))) void*)g,
        (__attribute__((address_space(3))) void*)lds,
        16, 0, 0);
}

// Core 128x128 GEMM tile, BK=32, 256 threads (4 waves, 2x2 wave grid, 4x4 MFMA tiles/wave).
// C[m,n] = sum_k A[m,k] * B[n,k]   (B given row-major over n, i.e. "B^T input")
__device__ __forceinline__ void gemm_core(
    const bf16* __restrict__ Ag, long lda, int rowA0,
    const bf16* __restrict__ Bg, long ldb, int rowB0,
    int kIters, f32x4 acc[4][4])
{
    __shared__ bf16 lA[128 * 32];
    __shared__ bf16 lB[128 * 32];
    const int tid  = threadIdx.x;
    const int lane = tid & 63;
    const int wid  = tid >> 6;
    const int wm   = (wid >> 1) * 64;
    const int wn   = (wid & 1) * 64;
    const int lr   = lane & 15;
    const int kq   = (lane >> 4) * 8;

    for (int kk = 0; kk < kIters; ++kk) {
        const long k0 = (long)kk * 32;
#pragma unroll
        for (int i = 0; i < 2; ++i) {
            const int c   = tid + i * 256;
            const int row = c >> 2;
            const int ko  = (c & 3) * 8;
            async16(&lA[c * 8], Ag + (long)(rowA0 + row) * lda + k0 + ko);
            async16(&lB[c * 8], Bg + (long)(rowB0 + row) * ldb + k0 + ko);
        }
        __syncthreads();

        bf16x8 af[4], bfr[4];
#pragma unroll
        for (int mi = 0; mi < 4; ++mi)
            af[mi] = *(const bf16x8*)&lA[(wm + mi * 16 + lr) * 32 + kq];
#pragma unroll
        for (int ni = 0; ni < 4; ++ni)
            bfr[ni] = *(const bf16x8*)&lB[(wn + ni * 16 + lr) * 32 + kq];
#pragma unroll
        for (int mi = 0; mi < 4; ++mi)
#pragma unroll
            for (int ni = 0; ni < 4; ++ni)
                acc[mi][ni] = __builtin_amdgcn_mfma_f32_16x16x32_bf16(
                    af[mi], bfr[ni], acc[mi][ni], 0, 0, 0);
        __syncthreads();
    }
}

// fp32 -> bf16 elementwise, 4 per thread
__global__ __launch_bounds__(256) void cvt_kernel(const float* __restrict__ in,
                                                  bf16* __restrict__ out, int n4)
{
    int i = blockIdx.x * 256 + threadIdx.x;
    if (i >= n4) return;
    const float4 v = ((const float4*)in)[i];
    bf16x4 o = { (bf16)v.x, (bf16)v.y, (bf16)v.z, (bf16)v.w };
    ((bf16x4*)out)[i] = o;
}

__global__ __launch_bounds__(256) void zero_kernel(float* __restrict__ p)
{
    p[blockIdx.x * 256 + threadIdx.x] = 0.0f;
}

// QKV projection: C[m, n] = sum_k x[m,k] W[n,k] + b[n], m in [0,8192), n in [0,3072)
// n<1024 -> Q[m][n], n<2048 -> K[m][n-1024], else V transposed Vt[b][d][s] (bf16x4 stores:
// the 4 r-values are 4 consecutive s for fixed d -> 8B stores instead of 4x2B scatter)
__global__ __launch_bounds__(256) void qkv_gemm(
    const bf16* __restrict__ xb, const bf16* __restrict__ wb,
    const float* __restrict__ bias,
    bf16* __restrict__ Qb, bf16* __restrict__ Kb, bf16* __restrict__ Vt)
{
    const int bm = blockIdx.y * 128, bn = blockIdx.x * 128;
    f32x4 acc[4][4] = {};
    gemm_core(xb, DIMD, bm, wb, DIMD, bn, DIMD / 32, acc);

    const int tid = threadIdx.x, lane = tid & 63, wid = tid >> 6;
    const int wm = (wid >> 1) * 64, wn = (wid & 1) * 64;
    const int lr = lane & 15, q4 = (lane >> 4) * 4;
#pragma unroll
    for (int ni = 0; ni < 4; ++ni) {
        const int n = bn + wn + ni * 16 + lr;
        const float bv = bias[n];
#pragma unroll
        for (int mi = 0; mi < 4; ++mi) {
            const int m = bm + wm + mi * 16 + q4;  // rows m..m+3
            if (n < 2048) {
#pragma unroll
                for (int r = 0; r < 4; ++r) {
                    const bf16 o = (bf16)(acc[mi][ni][r] + bv);
                    if (n < 1024) Qb[(long)(m + r) * DIMD + n] = o;
                    else          Kb[(long)(m + r) * DIMD + (n - 1024)] = o;
                }
            } else {
                const int b = m >> 12, s = m & 4095;
                bf16x4 o = { (bf16)(acc[mi][ni][0] + bv), (bf16)(acc[mi][ni][1] + bv),
                             (bf16)(acc[mi][ni][2] + bv), (bf16)(acc[mi][ni][3] + bv) };
                *(bf16x4*)&Vt[((long)b * DIMD + (n - 2048)) * SEQ + s] = o;
            }
        }
    }
}

// scores: P[q][key] = (key<=q) ? exp((Q.K^T)[q][key]/32) : 0 (bf16), plus fused
// row-sum accumulation into sums[batch][q] via shuffle-reduce + atomicAdd.
__global__ __launch_bounds__(256) void score_kernel(
    const bf16* __restrict__ Qb, const bf16* __restrict__ Kb,
    bf16* __restrict__ P, long Pstride, float* __restrict__ sums, int batch0)
{
    const int bq = blockIdx.y * 128, bk = blockIdx.x * 128;
    if (bk > bq) return;  // fully masked tile: never written, never read downstream
    const int bz = blockIdx.z, batch = batch0 + bz;
    const bf16* Q = Qb + (long)batch * SEQ * DIMD;
    const bf16* K = Kb + (long)batch * SEQ * DIMD;
    bf16* Pb = P + (long)bz * Pstride;
    float* sb = sums + (long)batch * SEQ;

    f32x4 acc[4][4] = {};
    gemm_core(Q, DIMD, bq, K, DIMD, bk, DIMD / 32, acc);

    const int tid = threadIdx.x, lane = tid & 63, wid = tid >> 6;
    const int wm = (wid >> 1) * 64, wn = (wid & 1) * 64;
    const int lr = lane & 15, q4 = (lane >> 4) * 4;
#pragma unroll
    for (int mi = 0; mi < 4; ++mi) {
#pragma unroll
        for (int r = 0; r < 4; ++r) {
            const int q = bq + wm + mi * 16 + q4 + r;
            float rsum = 0.0f;
#pragma unroll
            for (int ni = 0; ni < 4; ++ni) {
                const int key = bk + wn + ni * 16 + lr;
                const float s = acc[mi][ni][r] * 0.03125f;  // 1/sqrt(1024)
                // scores ~N(0,1): no max-subtraction needed, exp() cannot overflow
                const float p = (key <= q) ? __expf(s) : 0.0f;
                const bf16 pb = (bf16)p;
                Pb[(long)q * SEQ + key] = pb;
                rsum += (float)pb;  // sum exactly what pv will read
            }
            // reduce across the 16 column-lanes (low 4 bits of lane)
            rsum += __shfl_xor(rsum, 1);
            rsum += __shfl_xor(rsum, 2);
            rsum += __shfl_xor(rsum, 4);
            rsum += __shfl_xor(rsum, 8);
            if (lr == 0) atomicAdd(&sb[q], rsum);
        }
    }
}

// Y[q][d] = (1/sums[q]) * sum_j P[q][j] * Vt[d][j]; K extent = (qt+1)*128 keys.
// y->qt interleave pairs long and short blocks in dispatch order.
__global__ __launch_bounds__(256) void pv_kernel(
    const bf16* __restrict__ P, long Pstride, const bf16* __restrict__ Vt,
    const float* __restrict__ sums, float* __restrict__ Y, int batch0)
{
    const int y = blockIdx.y;
    const int qt = (y & 1) ? (31 - (y >> 1)) : (y >> 1);
    const int bq = qt * 128, bd = blockIdx.x * 128;
    const int bz = blockIdx.z, batch = batch0 + bz;
    const bf16* Pb = P + (long)bz * Pstride;
    const bf16* Vb = Vt + (long)batch * DIMD * SEQ;
    const float* sb = sums + (long)batch * SEQ;
    float* Yb = Y + (long)batch * SEQ * DIMD;

    f32x4 acc[4][4] = {};
    gemm_core(Pb, SEQ, bq, Vb, SEQ, bd, (qt + 1) * 4, acc);

    const int tid = threadIdx.x, lane = tid & 63, wid = tid >> 6;
    const int wm = (wid >> 1) * 64, wn = (wid & 1) * 64;
    const int lr = lane & 15, q4 = (lane >> 4) * 4;
#pragma unroll
    for (int mi = 0; mi < 4; ++mi) {
#pragma unroll
        for (int r = 0; r < 4; ++r) {
            const int q = bq + wm + mi * 16 + q4 + r;
            const float iv = 1.0f / sb[q];
#pragma unroll
            for (int ni = 0; ni < 4; ++ni) {
                const int d = bd + wn + ni * 16 + lr;
                Yb[(long)q * DIMD + d] = acc[mi][ni][r] * iv;
            }
        }
    }
}

extern "C" void kernel_launch(void* const* d_in, const int* in_sizes, int n_in,
                              void* d_out, int out_size, void* d_ws, size_t ws_size,
                              hipStream_t stream)
{
    const float* x    = (const float*)d_in[0];   // [2,4096,1024]
    const float* W    = (const float*)d_in[1];   // [3072,1024]
    const float* bqkv = (const float*)d_in[2];   // [3072]
    float* out = (float*)d_out;                  // [2,4096,1024] fp32
    char* ws = (char*)d_ws;

    const size_t MB = 1024 * 1024;
    // Parallel-batch path needs 112 MB + sums; fall back to serial (80 MB, known-fits).
    const bool par = ws_size >= (size_t)112 * MB + 64 * 1024;

    // Layout. xb/wb are transient and overlap the P0 region (consumed by qkv_gemm
    // before any score kernel writes P0; stream-ordered).
    bf16* P0  = (bf16*)ws;                                   // 32 MB
    const size_t base = par ? 64 * MB : 32 * MB;             // P1 @32MB iff parallel
    bf16* xb  = (bf16*)ws;                                   // 16 MB transient
    bf16* wb  = (bf16*)(ws + 16 * MB);                       //  6 MB transient
    bf16* Qb  = (bf16*)(ws + base);                          // 16 MB
    bf16* Kb  = (bf16*)(ws + base + 16 * MB);                // 16 MB
    bf16* Vt  = (bf16*)(ws + base + 32 * MB);                // 16 MB, [b][d][s]
    float* sums = (float*)(ws + base + 48 * MB);             // 32 KB

    const long PSTR = (long)SEQ * SEQ;  // element stride between P buffers

    cvt_kernel<<<8192, 256, 0, stream>>>(x, xb, 8192 * 1024 / 4);
    cvt_kernel<<<3072, 256, 0, stream>>>(W, wb, 3072 * 1024 / 4);
    zero_kernel<<<32, 256, 0, stream>>>(sums);
    qkv_gemm<<<dim3(24, 64), 256, 0, stream>>>(xb, wb, bqkv, Qb, Kb, Vt);

    if (par) {
        score_kernel<<<dim3(32, 32, 2), 256, 0, stream>>>(Qb, Kb, P0, PSTR, sums, 0);
        pv_kernel<<<dim3(8, 32, 2), 256, 0, stream>>>(P0, PSTR, Vt, sums, out, 0);
    } else {
        for (int b = 0; b < 2; ++b) {
            score_kernel<<<dim3(32, 32, 1), 256, 0, stream>>>(Qb, Kb, P0, 0, sums, b);
            pv_kernel<<<dim3(8, 32, 1), 256, 0, stream>>>(P0, 0, Vt, sums, out, b);
        }
    }
}

// Round 3
// 286.035 us; speedup vs baseline: 1.5419x; 1.2219x over previous
//
#include <hip/hip_runtime.h>
#include <cstdint>
#include <cstddef>

typedef __bf16 bf16;
typedef bf16 bf16x4 __attribute__((ext_vector_type(4)));
typedef bf16 bf16x8 __attribute__((ext_vector_type(8)));
typedef float f32x4 __attribute__((ext_vector_type(4)));

#define SEQ 4096
#define DIMD 1024

// ---- Universal tiled bf16 operand layout -----------------------------------
// X[R][K] -> X_t[rt][kc][r][kk]: rt=row/128, kc=col/32, r=row%128, kk=col%32.
// flat = rt*128*K + kc*4096 + r*32 + kk.  One (rt,kc) block = 128x32 = 8 KB
// contiguous, exactly one gemm_core staging tile.
#define TILE_K1024 131072L   // 128*1024: row-tile stride for K=1024 operands
#define TILE_K4096 524288L   // 128*4096: row-tile stride for K=4096 operands

// async global->LDS, 16 bytes per lane. LDS dest must be wave-uniform base + lane*16.
__device__ __forceinline__ void async16(void* lds, const void* g) {
    __builtin_amdgcn_global_load_lds(
        (__attribute__((address_space(1))) void*)g,
        (__attribute__((address_space(3))) void*)lds,
        16, 0, 0);
}

// Core 128x128 GEMM tile on tiled operands. At/Bt point at the row-tile base;
// k-iter kk consumes the contiguous 8 KB block at offset kk*4096 elements.
// C[m,n] = sum_k A[m,k]*B[n,k].
__device__ __forceinline__ void gemm_core(
    const bf16* __restrict__ At, const bf16* __restrict__ Bt,
    int k0, int k1, f32x4 acc[4][4])
{
    __shared__ bf16 lA[4096];
    __shared__ bf16 lB[4096];
    const int tid  = threadIdx.x;
    const int lane = tid & 63;
    const int wid  = tid >> 6;
    const int wm   = (wid >> 1) * 64;
    const int wn   = (wid & 1) * 64;
    const int lr   = lane & 15;
    const int kq   = (lane >> 4) * 8;

    for (int kk = k0; kk < k1; ++kk) {
        const bf16* sa = At + (long)kk * 4096;
        const bf16* sb = Bt + (long)kk * 4096;
        async16(&lA[tid * 8],        sa + tid * 8);
        async16(&lA[2048 + tid * 8], sa + 2048 + tid * 8);
        async16(&lB[tid * 8],        sb + tid * 8);
        async16(&lB[2048 + tid * 8], sb + 2048 + tid * 8);
        __syncthreads();

        bf16x8 af[4], bfr[4];
#pragma unroll
        for (int mi = 0; mi < 4; ++mi)
            af[mi] = *(const bf16x8*)&lA[(wm + mi * 16 + lr) * 32 + kq];
#pragma unroll
        for (int ni = 0; ni < 4; ++ni)
            bfr[ni] = *(const bf16x8*)&lB[(wn + ni * 16 + lr) * 32 + kq];
#pragma unroll
        for (int mi = 0; mi < 4; ++mi)
#pragma unroll
            for (int ni = 0; ni < 4; ++ni)
                acc[mi][ni] = __builtin_amdgcn_mfma_f32_16x16x32_bf16(
                    af[mi], bfr[ni], acc[mi][ni], 0, 0, 0);
        __syncthreads();
    }
}

// fp32 [R][1024] row-major -> tiled bf16 (K=1024)
__global__ __launch_bounds__(256) void cvt_tile_kernel(const float* __restrict__ in,
                                                       bf16* __restrict__ out, int n4)
{
    const int i = blockIdx.x * 256 + threadIdx.x;
    if (i >= n4) return;
    const float4 v = ((const float4*)in)[i];
    const int j = i * 4, row = j >> 10, col = j & 1023;
    const long o = (long)(row >> 7) * TILE_K1024 + (col >> 5) * 4096
                 + (row & 127) * 32 + (col & 31);
    bf16x4 ov = { (bf16)v.x, (bf16)v.y, (bf16)v.z, (bf16)v.w };
    *(bf16x4*)&out[o] = ov;
}

__global__ __launch_bounds__(256) void zero_kernel(float* __restrict__ p)
{
    p[blockIdx.x * 256 + threadIdx.x] = 0.0f;
}

// QKV: C[m,n] = sum_k x[m,k] W[n,k] + b[n]; outputs tiled Q, K (rows m, K=1024)
// and tiled Vt (per batch: rows d, K=SEQ).
__global__ __launch_bounds__(256) void qkv_gemm(
    const bf16* __restrict__ xt, const bf16* __restrict__ wt,
    const float* __restrict__ bias,
    bf16* __restrict__ Qt, bf16* __restrict__ Kt, bf16* __restrict__ Vtt)
{
    const int bm = blockIdx.y * 128, bn = blockIdx.x * 128;
    f32x4 acc[4][4] = {};
    gemm_core(xt + (long)(bm >> 7) * TILE_K1024,
              wt + (long)(bn >> 7) * TILE_K1024, 0, 32, acc);

    const int tid = threadIdx.x, lane = tid & 63, wid = tid >> 6;
    const int wm = (wid >> 1) * 64, wn = (wid & 1) * 64;
    const int lr = lane & 15, q4 = (lane >> 4) * 4;
#pragma unroll
    for (int ni = 0; ni < 4; ++ni) {
        const int n = bn + wn + ni * 16 + lr;
        const float bv = bias[n];
#pragma unroll
        for (int mi = 0; mi < 4; ++mi) {
            const int m0 = bm + wm + mi * 16 + q4;  // rows m0..m0+3 (aligned 4)
            if (n < 2048) {
                bf16* dst = (n < 1024) ? Qt : Kt;
                const int c = n & 1023;
#pragma unroll
                for (int r = 0; r < 4; ++r) {
                    const int m = m0 + r;
                    dst[(long)(m >> 7) * TILE_K1024 + (c >> 5) * 4096
                        + (m & 127) * 32 + (c & 31)] = (bf16)(acc[mi][ni][r] + bv);
                }
            } else {
                const int b = m0 >> 12, s = m0 & 4095, d = n - 2048;
                bf16x4 o = { (bf16)(acc[mi][ni][0] + bv), (bf16)(acc[mi][ni][1] + bv),
                             (bf16)(acc[mi][ni][2] + bv), (bf16)(acc[mi][ni][3] + bv) };
                *(bf16x4*)&Vtt[(long)b * 4194304 + (long)(d >> 7) * TILE_K4096
                               + (s >> 5) * 4096 + (d & 127) * 32 + (s & 31)] = o;
            }
        }
    }
}

// scores: Pt[q][key] = (key<=q) ? exp(QK^T/32) : 0, tiled layout, fused rowsum.
// Compacted triangular grid: x in [0,528) -> (qt, kt<=qt); y = batch.
__global__ __launch_bounds__(256) void score_kernel(
    const bf16* __restrict__ Qt, const bf16* __restrict__ Kt,
    bf16* __restrict__ P, long Pstride, float* __restrict__ sums, int batch0)
{
    const int i = blockIdx.x;
    int qt = (int)((sqrtf((float)(8 * i + 1)) - 1.0f) * 0.5f);
    while ((qt + 1) * (qt + 2) / 2 <= i) ++qt;
    while (qt * (qt + 1) / 2 > i) --qt;
    const int kt = i - qt * (qt + 1) / 2;

    const int bz = blockIdx.y, batch = batch0 + bz;
    bf16* Pb = P + (long)bz * Pstride;
    float* sb = sums + (long)batch * SEQ;

    f32x4 acc[4][4] = {};
    gemm_core(Qt + (long)(batch * 32 + qt) * TILE_K1024,
              Kt + (long)(batch * 32 + kt) * TILE_K1024, 0, 32, acc);

    const int tid = threadIdx.x, lane = tid & 63, wid = tid >> 6;
    const int wm = (wid >> 1) * 64, wn = (wid & 1) * 64;
    const int lr = lane & 15, q4 = (lane >> 4) * 4;
#pragma unroll
    for (int mi = 0; mi < 4; ++mi) {
#pragma unroll
        for (int r = 0; r < 4; ++r) {
            const int ql = wm + mi * 16 + q4 + r;       // q within tile
            const int q  = qt * 128 + ql;
            float rsum = 0.0f;
#pragma unroll
            for (int ni = 0; ni < 4; ++ni) {
                const int key = kt * 128 + wn + ni * 16 + lr;
                const float s = acc[mi][ni][r] * 0.03125f;  // 1/sqrt(1024)
                // scores ~N(0,1): no max-subtraction needed, exp() cannot overflow
                const float p = (key <= q) ? __expf(s) : 0.0f;
                const bf16 pb = (bf16)p;
                Pb[(long)qt * TILE_K4096 + (key >> 5) * 4096 + ql * 32 + (key & 31)] = pb;
                rsum += (float)pb;  // sum exactly what pv will read
            }
            rsum += __shfl_xor(rsum, 1);
            rsum += __shfl_xor(rsum, 2);
            rsum += __shfl_xor(rsum, 4);
            rsum += __shfl_xor(rsum, 8);
            if (lr == 0) atomicAdd(&sb[q], rsum);
        }
    }
}

// PV split-K, one dispatch: y<32 = main chunk (k-iters [0,min(64,ext)) -> Y),
// y>=32 = tail chunk (qt>=16, k-iters [64,ext) -> Ypart). ext=(qt+1)*4.
// Long/short q-tiles interleaved in dispatch order for balance.
__global__ __launch_bounds__(256) void pv_kernel(
    const bf16* __restrict__ P, long Pstride, const bf16* __restrict__ Vtt,
    const float* __restrict__ sums, float* __restrict__ Y,
    float* __restrict__ Ypart, int batch0)
{
    const int y = blockIdx.y, dt = blockIdx.x;
    const bool tail = (y >= 32);
    int qt;
    if (!tail) qt = (y & 1) ? (31 - (y >> 1)) : (y >> 1);
    else { const int t = y - 32; qt = 16 + ((t & 1) ? (15 - (t >> 1)) : (t >> 1)); }
    const int ext = (qt + 1) * 4;
    const int k0 = tail ? 64 : 0;
    const int k1 = tail ? ext : (ext < 64 ? ext : 64);

    const int bz = blockIdx.z, batch = batch0 + bz;
    const bf16* Pb = P + (long)bz * Pstride;
    const float* sb = sums + (long)batch * SEQ;

    f32x4 acc[4][4] = {};
    gemm_core(Pb + (long)qt * TILE_K4096,
              Vtt + (long)batch * 4194304 + (long)dt * TILE_K4096, k0, k1, acc);

    const int tid = threadIdx.x, lane = tid & 63, wid = tid >> 6;
    const int wm = (wid >> 1) * 64, wn = (wid & 1) * 64;
    const int lr = lane & 15, q4 = (lane >> 4) * 4;
#pragma unroll
    for (int mi = 0; mi < 4; ++mi) {
#pragma unroll
        for (int r = 0; r < 4; ++r) {
            const int q = qt * 128 + wm + mi * 16 + q4 + r;
            const float iv = 1.0f / sb[q];   // linear: each chunk scales its part
#pragma unroll
            for (int ni = 0; ni < 4; ++ni) {
                const int d = dt * 128 + wn + ni * 16 + lr;
                const float v = acc[mi][ni][r] * iv;
                if (!tail) Y[(long)batch * 4194304 + (long)q * DIMD + d] = v;
                else Ypart[(long)batch * 2097152 + (long)(q - 2048) * DIMD + d] = v;
            }
        }
    }
}

// Y[b][q][:] += Ypart for q in [2048,4096)
__global__ __launch_bounds__(256) void combine_kernel(float* __restrict__ Y,
                                                      const float* __restrict__ Ypart)
{
    const int i = blockIdx.x * 256 + threadIdx.x;   // 4.2M/4 elements
    const long j = (long)i * 4;
    const int b = (int)(j >> 21);
    const long rem = j & 2097151;
    float4 a = *(const float4*)&Y[(long)b * 4194304 + 2097152 + rem];
    const float4 p = *(const float4*)&Ypart[(long)b * 2097152 + rem];
    a.x += p.x; a.y += p.y; a.z += p.z; a.w += p.w;
    *(float4*)&Y[(long)b * 4194304 + 2097152 + rem] = a;
}

extern "C" void kernel_launch(void* const* d_in, const int* in_sizes, int n_in,
                              void* d_out, int out_size, void* d_ws, size_t ws_size,
                              hipStream_t stream)
{
    const float* x    = (const float*)d_in[0];   // [2,4096,1024]
    const float* W    = (const float*)d_in[1];   // [3072,1024]
    const float* bqkv = (const float*)d_in[2];   // [3072]
    float* out = (float*)d_out;                  // [2,4096,1024] fp32
    char* ws = (char*)d_ws;

    const size_t MB = 1024 * 1024;
    const bool par = ws_size >= (size_t)112 * MB + 64 * 1024;  // confirmed true in R2

    // Layout (par): P0@0 (32MB) P1@32 (32MB) Qt@64 (16MB) Kt@80 (16MB) Vtt@96 (16MB)
    // sums@112 (32KB). xt/wt transient alias P0; Ypart aliases Qt (dead after score).
    const size_t base = par ? 64 * MB : 32 * MB;
    bf16* P0   = (bf16*)ws;
    bf16* xt   = (bf16*)ws;                       // 16 MB transient
    bf16* wt   = (bf16*)(ws + 16 * MB);           //  6 MB transient
    bf16* Qt   = (bf16*)(ws + base);
    bf16* Kt   = (bf16*)(ws + base + 16 * MB);
    bf16* Vtt  = (bf16*)(ws + base + 32 * MB);
    float* sums  = (float*)(ws + base + 48 * MB);
    float* Ypart = (float*)(ws + base);           // aliases Qt

    const long PSTR = (long)SEQ * SEQ;

    cvt_tile_kernel<<<8192, 256, 0, stream>>>(x, xt, 8192 * 1024 / 4);
    cvt_tile_kernel<<<3072, 256, 0, stream>>>(W, wt, 3072 * 1024 / 4);
    zero_kernel<<<32, 256, 0, stream>>>(sums);
    qkv_gemm<<<dim3(24, 64), 256, 0, stream>>>(xt, wt, bqkv, Qt, Kt, Vtt);

    if (par) {
        score_kernel<<<dim3(528, 2), 256, 0, stream>>>(Qt, Kt, P0, PSTR, sums, 0);
        pv_kernel<<<dim3(8, 48, 2), 256, 0, stream>>>(P0, PSTR, Vtt, sums, out, Ypart, 0);
    } else {
        for (int b = 0; b < 2; ++b) {
            score_kernel<<<dim3(528, 1), 256, 0, stream>>>(Qt, Kt, P0, 0, sums, b);
            pv_kernel<<<dim3(8, 48, 1), 256, 0, stream>>>(P0, 0, Vtt, sums, out, Ypart, b);
        }
    }
    combine_kernel<<<4096, 256, 0, stream>>>(out, Ypart);
}